// Round 13
// baseline (298.421 us; speedup 1.0000x reference)
//
#include <hip/hip_runtime.h>
#include <stdint.h>

#define B_ 256
#define I_ 1024
#define N_ 1024
#define T_ 100
#define TP_ 128            // T padded to 128 (M-tile)
#define TOUT 99            // output length T-1
#define BN_ 64             // n-tile per block
#define KEEP (3897.0f/4096.0f)   // (4096-199)/4096, exact in fp32
#define VMAXF 8388607.0f
#define VMINF (-8388607.0f)

typedef __attribute__((ext_vector_type(4))) int i32x4;

// workspace layout (bytes)
#define WS_MAX 0
#define WS_QB  4096
#define WS_QW  8192                         // i8 [N][I] = 1 MB
#define WS_ST  (8192 + 1024*1024 + 4096)    // i8 [B][128][I] = 33.5 MB

__global__ void maxabs_k(const float* __restrict__ w, unsigned* __restrict__ mx) {
  float m = 0.f;
  int stride = gridDim.x * blockDim.x;
  for (int i = blockIdx.x * blockDim.x + threadIdx.x; i < N_ * I_; i += stride)
    m = fmaxf(m, fabsf(w[i]));
  #pragma unroll
  for (int off = 32; off > 0; off >>= 1)
    m = fmaxf(m, __shfl_xor(m, off));
  if ((threadIdx.x & 63) == 0) atomicMax(mx, __float_as_uint(m));
}

// qw_i8 = (trunc(w*scale) >> 1)  in [-128,127]; true qw = qw_i8 * 128
__global__ void quant_k(const float* __restrict__ w, const float* __restrict__ bias,
                        const unsigned* __restrict__ mx,
                        signed char* __restrict__ qw, float* __restrict__ qb) {
  const float scale = 255.0f / __uint_as_float(*mx);
  int gid = blockIdx.x * blockDim.x + threadIdx.x;
  int stride = gridDim.x * blockDim.x;
  for (int idx = gid; idx < N_ * I_; idx += stride) {
    int qi = (int)truncf(__fmul_rn(w[idx], scale));   // [-255,255]
    qw[idx] = (signed char)(qi >> 1);                 // arith shift == floor(x/2)
  }
  if (gid < N_)
    qb[gid] = truncf(__fmul_rn(bias[gid], scale)) * 64.0f;
}

// spikes [B,I,T] int32 -> ST [B,128,I] i8 (zero-padded t>=100)
__global__ void spk_transpose_k(const int* __restrict__ spk, signed char* __restrict__ st) {
  __shared__ unsigned char tile[TP_][80];   // stride 80: 16B-aligned rows
  const int b = blockIdx.y;
  const int i0 = blockIdx.x * 64;
  for (int idx = threadIdx.x; idx < 28 * 64; idx += 256)
    tile[100 + (idx >> 6)][idx & 63] = 0;
  // phase 1: 64 rows x 25 int4 (16B coalesced loads along t)
  for (int idx = threadIdx.x; idx < 64 * 25; idx += 256) {
    int il = idx / 25, c = idx - il * 25;
    const int4 v = *(const int4*)(spk + ((size_t)(b * I_ + i0 + il)) * T_ + 4 * c);
    int t = 4 * c;
    tile[t + 0][il] = (unsigned char)v.x;   // spikes are 0/1
    tile[t + 1][il] = (unsigned char)v.y;
    tile[t + 2][il] = (unsigned char)v.z;
    tile[t + 3][il] = (unsigned char)v.w;
  }
  __syncthreads();
  // phase 2: 128 t-rows x 4 uint4 chunks, coalesced 16B stores
  for (int idx = threadIdx.x; idx < 128 * 4; idx += 256) {
    int t = idx >> 2, q = idx & 3;
    uint4 u = *(const uint4*)&tile[t][q * 16];
    *(uint4*)(st + ((size_t)(b * 128 + t)) * I_ + i0 + q * 16) = u;
  }
}

// One block per (b, 64-wide n-tile): i8 GEMM WI[128t][64n] then in-LDS LIF scan.
// LDS: 3 x { A [128][64]i8 (8KB) + B [64][64]i8 (4KB) } = 36 KB rotating;
// epilogue aliases smem as WI f32[128][65] (33280 B). 4 blocks/CU.
// Pipeline: ONE barrier per k-step, vmcnt(3) counted wait, 2-step prefetch.
__global__ __launch_bounds__(256, 4)
void gemm_scan_k(const signed char* __restrict__ st,
                 const signed char* __restrict__ qw,
                 const float* __restrict__ qb,
                 const unsigned* __restrict__ mx,
                 float* __restrict__ out) {
  __shared__ __align__(16) char smem[36864];

  // bijective XCD swizzle: XCD c gets b in [c*32,(c+1)*32) x all 16 n-tiles
  const int bid = blockIdx.x;
  const int swz = (bid & 7) * 512 + (bid >> 3);
  const int b  = swz >> 4;
  const int n0 = (swz & 15) * BN_;

  const int tid  = threadIdx.x;
  const int lane = tid & 63;
  const int wv   = tid >> 6;
  const int wr = wv >> 1, wc = wv & 1;   // 2x2 wave grid; wave tile 64t x 32n
  const int lrow = lane & 15;
  const int ls   = lane >> 4;            // 16B k-slot 0..3

  i32x4 acc[4][2];
  #pragma unroll
  for (int i = 0; i < 4; ++i)
    #pragma unroll
    for (int j = 0; j < 2; ++j)
      acc[i][j] = (i32x4){0, 0, 0, 0};

  const char* stB = (const char*)st + (size_t)b * TP_ * I_;
  const char* qwB = (const char*)qw + (size_t)n0 * I_;

  // staging sources (ks-invariant), inverse-swizzled: LDS[row][slot q] = G[row][q ^ ((row>>1)&3)]
  const char* gA[2]; const char* gB1;
  #pragma unroll
  for (int j = 0; j < 2; ++j) {
    int slot = j * 256 + tid;            // 512 slots of 16B (A = 8KB)
    int row = slot >> 2, s = slot & 3;   // 4 slots per 64B row
    gA[j] = stB + (size_t)row * I_ + ((s ^ ((row >> 1) & 3)) << 4);
  }
  { int slot = tid;                      // 256 slots (B = 4KB)
    int row = slot >> 2, s = slot & 3;
    gB1 = qwB + (size_t)row * I_ + ((s ^ ((row >> 1) & 3)) << 4); }

  // fragment read offsets (swizzled; 2-way bank aliasing = free)
  int offA[4], offB[2];
  #pragma unroll
  for (int mi = 0; mi < 4; ++mi) {
    int row = wr * 64 + mi * 16 + lrow;
    offA[mi] = row * 64 + ((ls ^ ((row >> 1) & 3)) << 4);
  }
  #pragma unroll
  for (int ni = 0; ni < 2; ++ni) {
    int row = wc * 32 + ni * 16 + lrow;
    offB[ni] = 8192 + row * 64 + ((ls ^ ((row >> 1) & 3)) << 4);
  }

  // 3 gload_lds per thread per k-step (2 A + 1 B); dest = uniform base + lane*16
  #define STAGE(bufbase, ksrc) do {                                                   \
    const int g_ = (ksrc) * 64;                                                       \
    __builtin_amdgcn_global_load_lds(                                                 \
        (const __attribute__((address_space(1))) void*)(gA[0] + g_),                  \
        (__attribute__((address_space(3))) void*)(smem + (bufbase) + wv * 1024), 16, 0, 0); \
    __builtin_amdgcn_global_load_lds(                                                 \
        (const __attribute__((address_space(1))) void*)(gA[1] + g_),                  \
        (__attribute__((address_space(3))) void*)(smem + (bufbase) + 4096 + wv * 1024), 16, 0, 0); \
    __builtin_amdgcn_global_load_lds(                                                 \
        (const __attribute__((address_space(1))) void*)(gB1 + g_),                    \
        (__attribute__((address_space(3))) void*)(smem + (bufbase) + 8192 + wv * 1024), 16, 0, 0); \
  } while (0)

  STAGE(0, 0);
  STAGE(12288, 1);
  int pr = 0, pn = 12288, ps = 24576;     // read / in-flight / stage-target
  for (int ks = 0; ks < 16; ++ks) {
    // buf pr's 3 loads (issued 2 steps ago) landed; pn's 3 may stay in flight
    asm volatile("s_waitcnt vmcnt(3)" ::: "memory");
    __builtin_amdgcn_sched_barrier(0);
    __builtin_amdgcn_s_barrier();        // all waves: pr staged AND prior reads of ps done
    __builtin_amdgcn_sched_barrier(0);

    STAGE(ps, (ks + 2) & 15);            // prefetch 2 ahead (wrap loads harmless)

    i32x4 af[4], bf[2];
    #pragma unroll
    for (int mi = 0; mi < 4; ++mi) af[mi] = *(const i32x4*)(smem + pr + offA[mi]);
    #pragma unroll
    for (int ni = 0; ni < 2; ++ni) bf[ni] = *(const i32x4*)(smem + pr + offB[ni]);
    asm volatile("s_waitcnt lgkmcnt(0)" ::: "memory");
    __builtin_amdgcn_sched_barrier(0);

    #pragma unroll
    for (int mi = 0; mi < 4; ++mi)
      #pragma unroll
      for (int ni = 0; ni < 2; ++ni)
        acc[mi][ni] = __builtin_amdgcn_mfma_i32_16x16x64_i8(af[mi], bf[ni], acc[mi][ni], 0, 0, 0);

    int tmp = pr; pr = pn; pn = ps; ps = tmp;
  }

  // drain wrap-prefetches; all waves' last reads done before WI aliases bufs
  asm volatile("s_waitcnt vmcnt(0)" ::: "memory");
  __builtin_amdgcn_sched_barrier(0);
  __builtin_amdgcn_s_barrier();

  // WI[t][n] = 128 * acc ; stride 65 floats (2-way-free stores and scan reads)
  float* WI = (float*)smem;
  #pragma unroll
  for (int mi = 0; mi < 4; ++mi) {
    int row = wr * 64 + mi * 16 + (lane >> 4) * 4;
    #pragma unroll
    for (int ni = 0; ni < 2; ++ni) {
      int col = wc * 32 + ni * 16 + (lane & 15);
      #pragma unroll
      for (int j = 0; j < 4; ++j)
        WI[(row + j) * 65 + col] = 128.0f * (float)acc[mi][ni][j];
    }
  }
  __syncthreads();

  // sequential LIF scan: only t=0..97 reach the output (delay slicing)
  if (tid < BN_) {
    const float scale = 255.0f / __uint_as_float(*mx);
    const float vth = truncf(scale) * 64.0f;
    const float qbn = qb[n0 + tid];
    float v = 0.f;
    float* orow = out + (size_t)(b * N_ + n0 + tid) * TOUT;
    orow[0] = 0.0f;
    for (int t = 0; t < 98; ++t) {
      float wi = WI[t * 65 + tid];
      v = __fadd_rn(__fadd_rn(__fmul_rn(v, KEEP), wi), qbn);  // ((v*keep)+wi)+qb, no FMA
      v = fminf(fmaxf(v, VMINF), VMAXF);
      orow[t + 1] = (v >= vth) ? 1.0f : 0.0f;
      if (v > vth) v = __fsub_rn(v, vth);
    }
  }
}

extern "C" void kernel_launch(void* const* d_in, const int* in_sizes, int n_in,
                              void* d_out, int out_size, void* d_ws, size_t ws_size,
                              hipStream_t stream) {
  const int*   spikes = (const int*)d_in[0];
  const float* weight = (const float*)d_in[1];
  const float* bias   = (const float*)d_in[2];
  float* out = (float*)d_out;
  char* ws = (char*)d_ws;

  unsigned*    mx = (unsigned*)(ws + WS_MAX);
  float*       qb = (float*)(ws + WS_QB);
  signed char* qw = (signed char*)(ws + WS_QW);
  signed char* st = (signed char*)(ws + WS_ST);

  hipMemsetAsync(mx, 0, 4, stream);
  maxabs_k<<<256, 256, 0, stream>>>(weight, mx);
  quant_k<<<1024, 256, 0, stream>>>(weight, bias, mx, qw, qb);
  spk_transpose_k<<<dim3(16, 256), 256, 0, stream>>>(spikes, st);
  gemm_scan_k<<<4096, 256, 0, stream>>>(st, qw, qb, mx, out);
}

// Round 14
// 273.914 us; speedup vs baseline: 1.0895x; 1.0895x over previous
//
#include <hip/hip_runtime.h>
#include <stdint.h>

#define B_ 256
#define I_ 1024
#define N_ 1024
#define T_ 100
#define TP_ 128            // T padded to 128 (M-tile)
#define TOUT 99            // output length T-1
#define KEEP (3897.0f/4096.0f)   // (4096-199)/4096, exact in fp32
#define VMAXF 8388607.0f
#define VMINF (-8388607.0f)

typedef __attribute__((ext_vector_type(4))) int i32x4;

// workspace layout (bytes)
#define WS_MAX 0
#define WS_QB  4096
#define WS_QW  8192                         // i8 [N][I] = 1 MB
#define WS_ST  (8192 + 1024*1024 + 4096)    // i8 [B][128][I] = 33.5 MB

// qw_i8 = (trunc(w*scale) >> 1)  in [-128,127]; true qw = qw_i8 * 128
__global__ void quant_k(const float* __restrict__ w, const float* __restrict__ bias,
                        const unsigned* __restrict__ mx,
                        signed char* __restrict__ qw, float* __restrict__ qb) {
  const float scale = 255.0f / __uint_as_float(*mx);
  int gid = blockIdx.x * blockDim.x + threadIdx.x;
  int stride = gridDim.x * blockDim.x;
  for (int idx = gid; idx < N_ * I_; idx += stride) {
    int qi = (int)truncf(__fmul_rn(w[idx], scale));   // [-255,255]
    qw[idx] = (signed char)(qi >> 1);                 // arith shift == floor(x/2)
  }
  if (gid < N_)
    qb[gid] = truncf(__fmul_rn(bias[gid], scale)) * 64.0f;
}

// spikes [B,I,T] int32 -> ST [B,128,I] i8 (zero-padded t>=100); x==16 slice: maxabs(w)
__global__ void spk_transpose_maxabs_k(const int* __restrict__ spk, signed char* __restrict__ st,
                                       const float* __restrict__ w, unsigned* __restrict__ mx) {
  if (blockIdx.x == 16) {                   // maxabs portion: 256 y-blocks cover 1M floats
    float m = 0.f;
    for (int i = blockIdx.y * 256 + threadIdx.x; i < N_ * I_; i += 256 * 256)
      m = fmaxf(m, fabsf(w[i]));
    #pragma unroll
    for (int off = 32; off > 0; off >>= 1)
      m = fmaxf(m, __shfl_xor(m, off));
    if ((threadIdx.x & 63) == 0) atomicMax(mx, __float_as_uint(m));
    return;
  }
  __shared__ unsigned char tile[TP_][80];   // stride 80: 16B-aligned rows
  const int b = blockIdx.y;
  const int i0 = blockIdx.x * 64;
  for (int idx = threadIdx.x; idx < 28 * 64; idx += 256)
    tile[100 + (idx >> 6)][idx & 63] = 0;
  // phase 1: 64 rows x 25 int4 (16B coalesced loads along t)
  for (int idx = threadIdx.x; idx < 64 * 25; idx += 256) {
    int il = idx / 25, c = idx - il * 25;
    const int4 v = *(const int4*)(spk + ((size_t)(b * I_ + i0 + il)) * T_ + 4 * c);
    int t = 4 * c;
    tile[t + 0][il] = (unsigned char)v.x;   // spikes are 0/1
    tile[t + 1][il] = (unsigned char)v.y;
    tile[t + 2][il] = (unsigned char)v.z;
    tile[t + 3][il] = (unsigned char)v.w;
  }
  __syncthreads();
  // phase 2: 128 t-rows x 4 uint4 chunks, coalesced 16B stores
  for (int idx = threadIdx.x; idx < 128 * 4; idx += 256) {
    int t = idx >> 2, q = idx & 3;
    uint4 u = *(const uint4*)&tile[t][q * 16];
    *(uint4*)(st + ((size_t)(b * 128 + t)) * I_ + i0 + q * 16) = u;
  }
}

// One block per (b, 128-wide n-pair): i8 GEMM WI[128t][2x64n] then in-LDS LIF scan.
// LDS: 2 x { A [128][64]i8 (8KB) + B0 [64][64]i8 (4KB) + B1 (4KB) } = 32 KB dbuf;
// epilogue aliases smem as WI f32[128][65] (33280 B), two sequential n-halves. 4 blocks/CU.
__global__ __launch_bounds__(256, 4)
void gemm_scan_k(const signed char* __restrict__ st,
                 const signed char* __restrict__ qw,
                 const float* __restrict__ qb,
                 const unsigned* __restrict__ mx,
                 float* __restrict__ out) {
  __shared__ __align__(16) char smem[33280];

  // bijective XCD swizzle: XCD c gets b in [c*32,(c+1)*32) x all 8 n-pairs
  const int bid = blockIdx.x;                 // grid 2048
  const int swz = (bid & 7) * 256 + (bid >> 3);
  const int b  = swz >> 3;
  const int n0 = (swz & 7) * 128;

  const int tid  = threadIdx.x;
  const int lane = tid & 63;
  const int wv   = tid >> 6;
  const int wr = wv >> 1, wc = wv & 1;   // 2x2: M-half x 32n-half (within each 64-tile)
  const int lrow = lane & 15;
  const int ls   = lane >> 4;            // 16B k-slot 0..3

  i32x4 acc0[4][2], acc1[4][2];
  #pragma unroll
  for (int i = 0; i < 4; ++i)
    #pragma unroll
    for (int j = 0; j < 2; ++j) { acc0[i][j] = (i32x4){0,0,0,0}; acc1[i][j] = (i32x4){0,0,0,0}; }

  const char* stB = (const char*)st + (size_t)b * TP_ * I_;
  const char* qwB = (const char*)qw + (size_t)n0 * I_;

  // staging sources (ks-invariant), inverse-swizzled: LDS[row][slot q] = G[row][q ^ ((row>>1)&3)]
  const char* gA[2]; const char* gB0; const char* gB1;
  #pragma unroll
  for (int j = 0; j < 2; ++j) {
    int slot = j * 256 + tid;            // A: 512 slots of 16B (8KB)
    int row = slot >> 2, s = slot & 3;   // 4 slots per 64B row
    gA[j] = stB + (size_t)row * I_ + ((s ^ ((row >> 1) & 3)) << 4);
  }
  { int row = tid >> 2, s = tid & 3;     // B tiles: 256 slots each (4KB)
    gB0 = qwB + (size_t)row * I_ + ((s ^ ((row >> 1) & 3)) << 4);
    gB1 = gB0 + (size_t)64 * I_; }

  // fragment read offsets (swizzled; 2-way bank aliasing = free)
  int offA[4], offB[2];
  #pragma unroll
  for (int mi = 0; mi < 4; ++mi) {
    int row = wr * 64 + mi * 16 + lrow;
    offA[mi] = row * 64 + ((ls ^ ((row >> 1) & 3)) << 4);
  }
  #pragma unroll
  for (int ni = 0; ni < 2; ++ni) {
    int row = wc * 32 + ni * 16 + lrow;
    offB[ni] = 8192 + row * 64 + ((ls ^ ((row >> 1) & 3)) << 4);   // B0; B1 = +4096
  }

  // 4 gload_lds per thread per k-step (2 A + B0 + B1); dest = uniform base + lane*16
  #define STAGE(bufbase, ksrc) do {                                                   \
    const int g_ = (ksrc) * 64;                                                       \
    __builtin_amdgcn_global_load_lds(                                                 \
        (const __attribute__((address_space(1))) void*)(gA[0] + g_),                  \
        (__attribute__((address_space(3))) void*)(smem + (bufbase) + wv * 1024), 16, 0, 0); \
    __builtin_amdgcn_global_load_lds(                                                 \
        (const __attribute__((address_space(1))) void*)(gA[1] + g_),                  \
        (__attribute__((address_space(3))) void*)(smem + (bufbase) + 4096 + wv * 1024), 16, 0, 0); \
    __builtin_amdgcn_global_load_lds(                                                 \
        (const __attribute__((address_space(1))) void*)(gB0 + g_),                    \
        (__attribute__((address_space(3))) void*)(smem + (bufbase) + 8192 + wv * 1024), 16, 0, 0); \
    __builtin_amdgcn_global_load_lds(                                                 \
        (const __attribute__((address_space(1))) void*)(gB1 + g_),                    \
        (__attribute__((address_space(3))) void*)(smem + (bufbase) + 12288 + wv * 1024), 16, 0, 0); \
  } while (0)

  STAGE(0, 0);
  int p = 0;
  for (int ks = 0; ks < 16; ++ks) {
    STAGE(16384 - p, (ks + 1) & 15);     // prefetch next (wrap harmless on last)
    __builtin_amdgcn_sched_barrier(0);
    asm volatile("s_waitcnt vmcnt(4)" ::: "memory");   // cur buffer's 4 loads landed
    __builtin_amdgcn_s_barrier();                      // all waves' cur loads landed
    __builtin_amdgcn_sched_barrier(0);

    i32x4 af[4], bf0[2], bf1[2];
    #pragma unroll
    for (int mi = 0; mi < 4; ++mi) af[mi] = *(const i32x4*)(smem + p + offA[mi]);
    #pragma unroll
    for (int ni = 0; ni < 2; ++ni) {
      bf0[ni] = *(const i32x4*)(smem + p + offB[ni]);
      bf1[ni] = *(const i32x4*)(smem + p + offB[ni] + 4096);
    }
    asm volatile("s_waitcnt lgkmcnt(0)" ::: "memory"); // my reads done
    __builtin_amdgcn_sched_barrier(0);
    __builtin_amdgcn_s_barrier();                      // all reads done -> cur overwritable

    #pragma unroll
    for (int mi = 0; mi < 4; ++mi)
      #pragma unroll
      for (int ni = 0; ni < 2; ++ni) {
        acc0[mi][ni] = __builtin_amdgcn_mfma_i32_16x16x64_i8(af[mi], bf0[ni], acc0[mi][ni], 0, 0, 0);
        acc1[mi][ni] = __builtin_amdgcn_mfma_i32_16x16x64_i8(af[mi], bf1[ni], acc1[mi][ni], 0, 0, 0);
      }
    p = 16384 - p;
  }

  // drain wrap-prefetch before aliasing LDS as WI
  asm volatile("s_waitcnt vmcnt(0)" ::: "memory");
  __builtin_amdgcn_sched_barrier(0);
  __builtin_amdgcn_s_barrier();

  // two sequential n-halves through WI f32[128][65]
  float* WI = (float*)smem;
  const float scale = 255.0f / __uint_as_float(*mx);
  const float vth = truncf(scale) * 64.0f;
  #pragma unroll
  for (int half = 0; half < 2; ++half) {
    #pragma unroll
    for (int mi = 0; mi < 4; ++mi) {
      int row = wr * 64 + mi * 16 + (lane >> 4) * 4;
      #pragma unroll
      for (int ni = 0; ni < 2; ++ni) {
        int col = wc * 32 + ni * 16 + (lane & 15);
        #pragma unroll
        for (int j = 0; j < 4; ++j)
          WI[(row + j) * 65 + col] =
              128.0f * (float)(half ? acc1[mi][ni][j] : acc0[mi][ni][j]);
      }
    }
    __syncthreads();
    if (tid < 64) {                       // sequential LIF scan, t=0..97 reach output
      const int n_idx = n0 + half * 64 + tid;
      const float qbn = qb[n_idx];
      float v = 0.f;
      float* orow = out + (size_t)(b * N_ + n_idx) * TOUT;
      orow[0] = 0.0f;
      for (int t = 0; t < 98; ++t) {
        float wi = WI[t * 65 + tid];
        v = __fadd_rn(__fadd_rn(__fmul_rn(v, KEEP), wi), qbn);  // ((v*keep)+wi)+qb, no FMA
        v = fminf(fmaxf(v, VMINF), VMAXF);
        orow[t + 1] = (v >= vth) ? 1.0f : 0.0f;
        if (v > vth) v = __fsub_rn(v, vth);
      }
    }
    __syncthreads();                      // scan reads done before next half's dump
  }
}

extern "C" void kernel_launch(void* const* d_in, const int* in_sizes, int n_in,
                              void* d_out, int out_size, void* d_ws, size_t ws_size,
                              hipStream_t stream) {
  const int*   spikes = (const int*)d_in[0];
  const float* weight = (const float*)d_in[1];
  const float* bias   = (const float*)d_in[2];
  float* out = (float*)d_out;
  char* ws = (char*)d_ws;

  unsigned*    mx = (unsigned*)(ws + WS_MAX);
  float*       qb = (float*)(ws + WS_QB);
  signed char* qw = (signed char*)(ws + WS_QW);
  signed char* st = (signed char*)(ws + WS_ST);

  hipMemsetAsync(mx, 0, 4, stream);
  spk_transpose_maxabs_k<<<dim3(17, 256), 256, 0, stream>>>(spikes, st, weight, mx);
  quant_k<<<1024, 256, 0, stream>>>(weight, bias, mx, qw, qb);
  gemm_scan_k<<<2048, 256, 0, stream>>>(st, qw, qb, mx, out);
}